// Round 7
// baseline (610.653 us; speedup 1.0000x reference)
//
#include <hip/hip_runtime.h>
#include <cstdint>
#include <cstddef>

// Sizes (fixed by the problem)
#define B_ 256
#define S_ 128
#define F_ 128
#define H_ 512
#define C_ 64
#define L_ 16
// 4H = 2048, 3H = 1536

typedef __attribute__((ext_vector_type(8))) short short8;   // 8 x bf16 (4 VGPRs) MFMA A/B frag
typedef __attribute__((ext_vector_type(4))) float f4;       // MFMA C/D frag
typedef __attribute__((ext_vector_type(4))) unsigned int u4;

__device__ __forceinline__ unsigned short f2bf(float f) {   // fp32 -> bf16 RNE
  union { float f; unsigned u; } v; v.f = f;
  unsigned r = v.u + 0x7fffu + ((v.u >> 16) & 1u);
  return (unsigned short)(r >> 16);
}
__device__ __forceinline__ float sigmoid_(float x) { return 1.0f / (1.0f + __expf(-x)); }
__device__ __forceinline__ float tanh_(float x) {
  x = fminf(15.f, fmaxf(-15.f, x));           // clamp: avoid inf/inf
  float e = __expf(2.f * x);
  return (e - 1.f) / (e + 1.f);
}

// ---------------------------------------------------------------------------
// Merged prep kernel: [0,2048) prepack_x | [2048,2696) prepack_w | [2696,2760) ctx
// Bounded loops only; no inter-block dependence; cannot hang.
// ---------------------------------------------------------------------------
__global__ void prep_kernel(const float* __restrict__ x, const float* __restrict__ W_hh,
                            const float* __restrict__ W_ih, const float* __restrict__ b_ih,
                            const float* __restrict__ b_hh, const float* __restrict__ context,
                            const float* __restrict__ w1, const float* __restrict__ b1,
                            const float* __restrict__ w2, const float* __restrict__ b2,
                            unsigned short* __restrict__ xfr, unsigned short* __restrict__ Wpk,
                            unsigned short* __restrict__ Wipk, float* __restrict__ bc,
                            float* __restrict__ ctxg) {
  int bid = blockIdx.x, tid = threadIdx.x;
  if (bid < 2048) {                       // ---- prepack_x ----
    int o8 = bid * 256 + tid;             // 524288 chunks
    int m = o8 & 15, kb = (o8 >> 4) & 15, Rg = (o8 >> 8) & 15, s = o8 >> 12;
    int b = Rg * 16 + m;
    const float* src = x + (b * S_ + s) * F_ + kb * 8;
    unsigned short* dst = xfr + o8 * 8;
#pragma unroll
    for (int j = 0; j < 8; j++) dst[j] = f2bf(src[j]);
    return;
  }
  if (bid < 2696) {                       // ---- prepack_w ----
    int t = (bid - 2048) * 256 + tid;
    if (t < 131072) {                     // W_hh: 32 ht * 4 g * 16 kit * 64 lanes
      int lane = t & 63, row = t >> 6;
      int kit = row & 15, gh = row >> 4;
      int g = gh & 3, ht = gh >> 2;
      int k0 = kit * 32 + ((lane >> 4) << 3);
      int col = g * 512 + ht * 16 + (lane & 15);
#pragma unroll
      for (int j = 0; j < 8; j++)
        Wpk[t * 8 + j] = f2bf(W_hh[(k0 + j) * 2048 + col]);
    } else if (t < 131072 + 32768) {      // W_ih: 32 ht * 4 g * 4 kit * 64 lanes
      int t2 = t - 131072;
      int lane = t2 & 63, row = t2 >> 6;
      int kit = row & 3, gh = row >> 2;
      int g = gh & 3, ht = gh >> 2;
      int k0 = kit * 32 + ((lane >> 4) << 3);
      int col = g * 512 + ht * 16 + (lane & 15);
#pragma unroll
      for (int j = 0; j < 8; j++)
        Wipk[t2 * 8 + j] = f2bf(W_ih[(k0 + j) * 2048 + col]);
    } else if (t < 131072 + 32768 + 2048) {
      int i = t - 131072 - 32768;
      bc[i] = b_ih[i] + b_hh[i];          // b_ih + b_hh folded together
    }
    return;
  }
  // ---- ctx: 4 batch rows/block; hid1 computed in-LDS (no global round trip) ----
  {
    __shared__ float hr[4 * H_];
    __shared__ float cc[4 * C_];
    int r0 = (bid - 2696) * 4, t = tid;
    if (t < 4 * C_) cc[t] = context[r0 * C_ + t];
    __syncthreads();
    for (int rj = t; rj < 4 * H_; rj += 256) {
      int r = rj >> 9, j = rj & 511;
      float acc = b1[j];
#pragma unroll 8
      for (int k = 0; k < C_; k++) acc = fmaf(cc[r * C_ + k], w1[k * H_ + j], acc);
      hr[rj] = fmaxf(acc, 0.f);
    }
    __syncthreads();
    float acc[4][6];
#pragma unroll
    for (int r = 0; r < 4; r++)
#pragma unroll
      for (int i = 0; i < 6; i++) acc[r][i] = 0.f;
    for (int k = 0; k < H_; k++) {
      float w[6];
#pragma unroll
      for (int i = 0; i < 6; i++) w[i] = w2[k * 1536 + t + i * 256];
#pragma unroll
      for (int r = 0; r < 4; r++) {
        float hv = hr[r * H_ + k];
#pragma unroll
        for (int i = 0; i < 6; i++) acc[r][i] = fmaf(hv, w[i], acc[r][i]);
      }
    }
#pragma unroll
    for (int r = 0; r < 4; r++)
#pragma unroll
      for (int i = 0; i < 6; i++) {
        int col = t + i * 256;
        ctxg[(r0 + r) * 1536 + col] = sigmoid_(acc[r][i] + b2[col]);
      }
  }
}

// ---------------------------------------------------------------------------
// Persistent LSTM kernel. Grid = 256 blocks (8 batch-tiles x 32 h-col tiles,
// STATIC R3 mapping: bt = blockIdx>>5, ht = blockIdx&31). No XCD detection,
// no dual path: h exchange via sc0 sc1 (L1/L2-bypass to coherent L3) -- the
// R3-proven placement-independent path. Step barrier is FLAG-based:
// arrive = one sc0 sc1 dword store of (t+1) into the block's own slot
// (32 flags = one 128B line per group); spin = one coalesced 32-lane
// agent-atomic load + __all. Monotonic flags, zeroed at launch.
// t=0 skips the h load entirely (h0 = 0), so h buffers need no init.
// ---------------------------------------------------------------------------
__global__ void __launch_bounds__(256) lstm_kernel(
    const unsigned short* __restrict__ xfr, const unsigned short* __restrict__ Wpk,
    const unsigned short* __restrict__ Wipk, const float* __restrict__ bc,
    const float* __restrict__ ctxg, float* __restrict__ hfinal,
    unsigned short* __restrict__ hb0, unsigned short* __restrict__ hb1,
    unsigned int* __restrict__ flags) {
  __shared__ __align__(16) unsigned short lds_h[16384];  // 2R x 16kit x 512  (32 KB)
  __shared__ __align__(16) unsigned short lds_x[4096];   // 2R x 4kit x 512   (8 KB)
  __shared__ float lds_g[128 * 17];                      // stride 17: conflict-light

  int tid = threadIdx.x, lane = tid & 63, wid = tid >> 6;
  int bt = blockIdx.x >> 5, ht = blockIdx.x & 31;        // exact R3 mapping

  // --- prologue: resident weight fragments (coalesced 16B/lane loads) ---
  short8 wf[16], wfi[4];
  {
    const short8* wp = (const short8*)Wpk + (ht * 4 + wid) * 16 * 64 + lane;
#pragma unroll
    for (int kit = 0; kit < 16; kit++) wf[kit] = wp[kit * 64];
    const short8* wip = (const short8*)Wipk + (ht * 4 + wid) * 4 * 64 + lane;
#pragma unroll
    for (int kit = 0; kit < 4; kit++) wfi[kit] = wip[kit * 64];
  }

  // --- per-thread elementwise state: 2 adjacent j's (one packed uint store) ---
  int bl = tid >> 3, jl0 = (tid & 7) * 2;       // bl in [0,32), jl0 even
  int bglob = bt * 32 + bl;
  int j0 = ht * 16 + jl0;
  float cst[2] = {0.f, 0.f};
  float ci_[2], cf_[2], co_[2], bi_[2], bf_[2], bg_[2], bo_[2];
#pragma unroll
  for (int p = 0; p < 2; p++) {
    int j = j0 + p;
    ci_[p] = ctxg[bglob * 1536 + j];
    cf_[p] = ctxg[bglob * 1536 + 512 + j];
    co_[p] = ctxg[bglob * 1536 + 1024 + j];
    bi_[p] = bc[j]; bf_[p] = bc[512 + j]; bg_[p] = bc[1024 + j]; bo_[p] = bc[1536 + j];
  }
  // fragment-major short offset of (bglob, j0); /2 -> packed uint offset
  int hoff2 = (((bt * 2 + (bl >> 4)) * 64 + ht * 2 + (jl0 >> 3)) * 128
               + (bl & 15) * 8 + (jl0 & 7)) >> 1;

  const unsigned int* fb = flags + bt * 32;      // this group's 32 flags (one 128B line)
  unsigned int* myflag = flags + bt * 32 + ht;

  // --- stage x(0) ---
#pragma unroll
  for (int i = 0; i < 2; i++) {
    int c = wid * 2 + i, R = c >> 2, kit = c & 3;
    u4 d = *(const u4*)(xfr + (size_t)((bt * 2 + R) * 16 + kit * 4) * 128 + lane * 8);
    *(u4*)(lds_x + (R * 4 + kit) * 512 + lane * 8) = d;
  }
  __syncthreads();

  for (int t = 0; t < S_; t++) {
    const unsigned short* hread = (t & 1) ? hb1 : hb0;   // double buffer
    unsigned short* hwrite = (t & 1) ? hb0 : hb1;

    f4 acc0a = {0.f, 0.f, 0.f, 0.f}, acc1a = {0.f, 0.f, 0.f, 0.f};
    f4 acc0b = {0.f, 0.f, 0.f, 0.f}, acc1b = {0.f, 0.f, 0.f, 0.f};

    // --- x MFMAs first (depend only on lds_x; fills time before the spin) ---
#pragma unroll
    for (int kit = 0; kit < 4; kit++) {
      short8 a0 = *(const short8*)(lds_x + kit * 512 + lane * 8);
      short8 a1 = *(const short8*)(lds_x + 2048 + kit * 512 + lane * 8);
      if (kit & 1) {
        acc0b = __builtin_amdgcn_mfma_f32_16x16x32_bf16(a0, wfi[kit], acc0b, 0, 0, 0);
        acc1b = __builtin_amdgcn_mfma_f32_16x16x32_bf16(a1, wfi[kit], acc1b, 0, 0, 0);
      } else {
        acc0a = __builtin_amdgcn_mfma_f32_16x16x32_bf16(a0, wfi[kit], acc0a, 0, 0, 0);
        acc1a = __builtin_amdgcn_mfma_f32_16x16x32_bf16(a1, wfi[kit], acc1a, 0, 0, 0);
      }
    }

    if (t > 0) {
      // --- spin: one coalesced 32-flag load per wave + __all (no atom-RMW) ---
      const unsigned int* fp = fb + (lane & 31);
      unsigned tgt = (unsigned)t;
      for (;;) {
        unsigned v = __hip_atomic_load(fp, __ATOMIC_RELAXED, __HIP_MEMORY_SCOPE_AGENT);
        if (__all(v >= tgt)) break;
      }

      // --- issue h bypass loads (coalesced dwordx4, L1/L2-bypass to L3) ---
      u4 tmp[8];
#pragma unroll
      for (int i = 0; i < 8; i++) {
        int c = wid * 8 + i, R = c >> 4, kit = c & 15;
        const unsigned int* src = (const unsigned int*)hread
            + (bt * 2 + R) * 4096 + kit * 256 + lane * 4;
        asm volatile("global_load_dwordx4 %0, %1, off sc0 sc1"
                     : "=v"(tmp[i]) : "v"(src) : "memory");
      }

      // --- drain h loads (values tied to the waitcnt), stage to LDS ---
      asm volatile("s_waitcnt vmcnt(0)"
                   : "+v"(tmp[0]), "+v"(tmp[1]), "+v"(tmp[2]), "+v"(tmp[3]),
                     "+v"(tmp[4]), "+v"(tmp[5]), "+v"(tmp[6]), "+v"(tmp[7])
                   :: "memory");
#pragma unroll
      for (int i = 0; i < 8; i++) {
        int c = wid * 8 + i, R = c >> 4, kit = c & 15;
        *(u4*)(lds_h + R * 8192 + kit * 512 + lane * 8) = tmp[i];
      }
      __syncthreads();

      // --- h MFMAs (split accumulators: halve the dependent-MFMA chain) ---
#pragma unroll
      for (int kit = 0; kit < 16; kit++) {
        short8 a0 = *(const short8*)(lds_h + kit * 512 + lane * 8);
        short8 a1 = *(const short8*)(lds_h + 8192 + kit * 512 + lane * 8);
        if (kit & 1) {
          acc0b = __builtin_amdgcn_mfma_f32_16x16x32_bf16(a0, wf[kit], acc0b, 0, 0, 0);
          acc1b = __builtin_amdgcn_mfma_f32_16x16x32_bf16(a1, wf[kit], acc1b, 0, 0, 0);
        } else {
          acc0a = __builtin_amdgcn_mfma_f32_16x16x32_bf16(a0, wf[kit], acc0a, 0, 0, 0);
          acc1a = __builtin_amdgcn_mfma_f32_16x16x32_bf16(a1, wf[kit], acc1a, 0, 0, 0);
        }
      }
    }

    // --- cross-gate combine: wave g publishes its gate block to LDS ---
    {
      f4 s0, s1;
#pragma unroll
      for (int r = 0; r < 4; r++) { s0[r] = acc0a[r] + acc0b[r]; s1[r] = acc1a[r] + acc1b[r]; }
      int q = lane >> 4, n = lane & 15;
#pragma unroll
      for (int r = 0; r < 4; r++) {
        lds_g[(wid * 32 + q * 4 + r) * 17 + n] = s0[r];          // rows 0..15
        lds_g[(wid * 32 + 16 + q * 4 + r) * 17 + n] = s1[r];     // rows 16..31
      }
    }
    __syncthreads();

    // --- elementwise LSTM cell update (fp32), packed bf16x2 write-through ---
    {
      float hv[2];
#pragma unroll
      for (int p = 0; p < 2; p++) {
        int jl = jl0 + p;
        float gi = lds_g[(0 * 32 + bl) * 17 + jl] + bi_[p];
        float gf = lds_g[(1 * 32 + bl) * 17 + jl] + bf_[p];
        float gg = lds_g[(2 * 32 + bl) * 17 + jl] + bg_[p];
        float go = lds_g[(3 * 32 + bl) * 17 + jl] + bo_[p];
        float iv = ci_[p] * sigmoid_(gi);
        float fv = cf_[p] * sigmoid_(gf);
        float ov = co_[p] * sigmoid_(go);
        float gv = tanh_(gg);
        float c = fv * cst[p] + iv * gv;
        cst[p] = c;
        hv[p] = ov * tanh_(c);
      }
      unsigned int packed = (unsigned)f2bf(hv[0]) | ((unsigned)f2bf(hv[1]) << 16);
      unsigned int* dst = (unsigned int*)hwrite + hoff2;
      asm volatile("global_store_dword %0, %1, off sc0 sc1"
                   :: "v"(dst), "v"(packed) : "memory");
      if (t == S_ - 1) {
        hfinal[bglob * H_ + j0] = hv[0];
        hfinal[bglob * H_ + j0 + 1] = hv[1];
      }
    }

    if (t < S_ - 1) {
      // --- arrive: drain h stores (all waves), then ONE flag store per block ---
      asm volatile("s_waitcnt vmcnt(0)" ::: "memory");
      __syncthreads();                       // all 4 waves' h stores are in L3
      if (tid == 0) {
        unsigned val = (unsigned)(t + 1);
        asm volatile("global_store_dword %0, %1, off sc0 sc1"
                     :: "v"(myflag), "v"(val) : "memory");
      }
      // --- stage x(t+1) while others arrive ---
#pragma unroll
      for (int i = 0; i < 2; i++) {
        int c = wid * 2 + i, R = c >> 2, kit = c & 3;
        u4 d = *(const u4*)(xfr + (size_t)((((t + 1) * 16) + bt * 2 + R) * 16 + kit * 4) * 128 + lane * 8);
        *(u4*)(lds_x + (R * 4 + kit) * 512 + lane * 8) = d;
      }
    }
    __syncthreads();   // gates lds_x(t+1) reads and lds_g reuse
  }
}

// ---------------------------------------------------------------------------
// VAE head: mu/lv = h@W + b, z = mu + eps*exp(0.5*lv),
// recon = relu(z@dec_w1+db1)@dec_w2+db2. One block per batch row, all fp32.
// ---------------------------------------------------------------------------
__global__ void post_kernel(const float* __restrict__ hfinal, const float* __restrict__ eps,
                            const float* __restrict__ mu_w, const float* __restrict__ mu_b,
                            const float* __restrict__ lv_w, const float* __restrict__ lv_b,
                            const float* __restrict__ dw1, const float* __restrict__ db1,
                            const float* __restrict__ dw2, const float* __restrict__ db2,
                            float* __restrict__ out) {
  __shared__ float sh[H_], sh1[H_], smu[L_], slv[L_], sz[L_];
  int b = blockIdx.x, t = threadIdx.x;
  for (int i = t; i < H_; i += 256) sh[i] = hfinal[b * H_ + i];
  __syncthreads();
  {
    int o = t >> 3, sub = t & 7, l = o & 15;   // 32 outputs x 8-lane partial dots
    const float* w = (o < 16) ? mu_w : lv_w;
    float acc = 0.f;
    int k0 = sub * 64;
#pragma unroll 8
    for (int k = k0; k < k0 + 64; k++) acc = fmaf(sh[k], w[k * L_ + l], acc);
#pragma unroll
    for (int d = 4; d >= 1; d >>= 1) acc += __shfl_down(acc, d, 8);
    if (sub == 0) {
      if (o < 16) { float v = acc + mu_b[l]; smu[l] = v; out[32768 + b * 16 + l] = v; }
      else        { float v = acc + lv_b[l]; slv[l] = v; out[36864 + b * 16 + l] = v; }
    }
  }
  __syncthreads();
  if (t < L_) sz[t] = smu[t] + eps[b * L_ + t] * __expf(0.5f * slv[t]);
  __syncthreads();
  for (int j = t; j < H_; j += 256) {
    float acc = db1[j];
#pragma unroll
    for (int l = 0; l < L_; l++) acc = fmaf(sz[l], dw1[l * H_ + j], acc);
    sh1[j] = fmaxf(acc, 0.f);
  }
  __syncthreads();
  if (t < F_) {
    float acc = db2[t];
    for (int k = 0; k < H_; k++) acc = fmaf(sh1[k], dw2[k * F_ + t], acc);
    out[b * F_ + t] = acc;
  }
}

// ---------------------------------------------------------------------------
extern "C" void kernel_launch(void* const* d_in, const int* in_sizes, int n_in,
                              void* d_out, int out_size, void* d_ws, size_t ws_size,
                              hipStream_t stream) {
  const float* x      = (const float*)d_in[0];
  const float* ctxin  = (const float*)d_in[1];
  const float* eps    = (const float*)d_in[2];
  const float* W_ih   = (const float*)d_in[3];
  const float* b_ih   = (const float*)d_in[4];
  const float* W_hh   = (const float*)d_in[5];
  const float* b_hh   = (const float*)d_in[6];
  const float* cg_w1  = (const float*)d_in[7];
  const float* cg_b1  = (const float*)d_in[8];
  const float* cg_w2  = (const float*)d_in[9];
  const float* cg_b2  = (const float*)d_in[10];
  const float* mu_w   = (const float*)d_in[11];
  const float* mu_b   = (const float*)d_in[12];
  const float* lv_w   = (const float*)d_in[13];
  const float* lv_b   = (const float*)d_in[14];
  const float* dec_w1 = (const float*)d_in[15];
  const float* dec_b1 = (const float*)d_in[16];
  const float* dec_w2 = (const float*)d_in[17];
  const float* dec_b2 = (const float*)d_in[18];
  float* out = (float*)d_out;

  char* ws = (char*)d_ws;
  size_t off = 0;
  auto alloc = [&](size_t bytes) { char* p = ws + off; off = (off + bytes + 255) & ~(size_t)255; return p; };

  unsigned int* flags = (unsigned int*)alloc(8 * 32 * 4);     // monotonic step flags
  size_t zero_bytes = off;
  unsigned short* hb0 = (unsigned short*)alloc(B_ * H_ * 2);  // 256 KB (no init: t=0 skips h read)
  unsigned short* hb1 = (unsigned short*)alloc(B_ * H_ * 2);  // 256 KB
  unsigned short* xfr  = (unsigned short*)alloc((size_t)B_ * S_ * F_ * 2);  // 8 MB
  unsigned short* Wpk  = (unsigned short*)alloc((size_t)H_ * 2048 * 2);     // 2 MB
  unsigned short* Wipk = (unsigned short*)alloc((size_t)F_ * 2048 * 2);     // 512 KB
  float* bc    = (float*)alloc(2048 * 4);
  float* ctxg  = (float*)alloc((size_t)B_ * 1536 * 4);
  float* hfin  = (float*)alloc((size_t)B_ * H_ * 4);
  (void)ws_size; (void)in_sizes; (void)n_in; (void)out_size;

  hipMemsetAsync(d_ws, 0, zero_bytes, stream);   // flags only

  prep_kernel<<<2760, 256, 0, stream>>>(x, W_hh, W_ih, b_ih, b_hh, ctxin,
                                        cg_w1, cg_b1, cg_w2, cg_b2,
                                        xfr, Wpk, Wipk, bc, ctxg);
  lstm_kernel<<<256, 256, 0, stream>>>(xfr, Wpk, Wipk, bc, ctxg, hfin, hb0, hb1,
                                       flags);
  post_kernel<<<256, 256, 0, stream>>>(hfin, eps, mu_w, mu_b, lv_w, lv_b,
                                       dec_w1, dec_b1, dec_w2, dec_b2, out);
}

// Round 8
// 588.747 us; speedup vs baseline: 1.0372x; 1.0372x over previous
//
#include <hip/hip_runtime.h>
#include <cstdint>
#include <cstddef>

// Sizes (fixed by the problem)
#define B_ 256
#define S_ 128
#define F_ 128
#define H_ 512
#define C_ 64
#define L_ 16
// 4H = 2048, 3H = 1536

typedef __attribute__((ext_vector_type(8))) short short8;   // 8 x bf16 (4 VGPRs) MFMA A/B frag
typedef __attribute__((ext_vector_type(4))) float f4;       // MFMA C/D frag
typedef __attribute__((ext_vector_type(4))) unsigned int u4;

__device__ __forceinline__ unsigned short f2bf(float f) {   // fp32 -> bf16 RNE
  union { float f; unsigned u; } v; v.f = f;
  unsigned r = v.u + 0x7fffu + ((v.u >> 16) & 1u);
  return (unsigned short)(r >> 16);
}
__device__ __forceinline__ float sigmoid_(float x) { return 1.0f / (1.0f + __expf(-x)); }
__device__ __forceinline__ float tanh_(float x) {
  x = fminf(15.f, fmaxf(-15.f, x));           // clamp: avoid inf/inf
  float e = __expf(2.f * x);
  return (e - 1.f) / (e + 1.f);
}

// ---------------------------------------------------------------------------
// Merged prep kernel: [0,2048) prepack_x | [2048,2696) prepack_w | [2696,2760) ctx
// Bounded loops only; no inter-block dependence; cannot hang.
// ---------------------------------------------------------------------------
__global__ void prep_kernel(const float* __restrict__ x, const float* __restrict__ W_hh,
                            const float* __restrict__ W_ih, const float* __restrict__ b_ih,
                            const float* __restrict__ b_hh, const float* __restrict__ context,
                            const float* __restrict__ w1, const float* __restrict__ b1,
                            const float* __restrict__ w2, const float* __restrict__ b2,
                            unsigned short* __restrict__ xfr, unsigned short* __restrict__ Wpk,
                            unsigned short* __restrict__ Wipk, float* __restrict__ bc,
                            float* __restrict__ ctxg) {
  int bid = blockIdx.x, tid = threadIdx.x;
  if (bid < 2048) {                       // ---- prepack_x ----
    int o8 = bid * 256 + tid;             // 524288 chunks
    int m = o8 & 15, kb = (o8 >> 4) & 15, Rg = (o8 >> 8) & 15, s = o8 >> 12;
    int b = Rg * 16 + m;
    const float* src = x + (b * S_ + s) * F_ + kb * 8;
    unsigned short* dst = xfr + o8 * 8;
#pragma unroll
    for (int j = 0; j < 8; j++) dst[j] = f2bf(src[j]);
    return;
  }
  if (bid < 2696) {                       // ---- prepack_w ----
    int t = (bid - 2048) * 256 + tid;
    if (t < 131072) {                     // W_hh: 32 ht * 4 g * 16 kit * 64 lanes
      int lane = t & 63, row = t >> 6;
      int kit = row & 15, gh = row >> 4;
      int g = gh & 3, ht = gh >> 2;
      int k0 = kit * 32 + ((lane >> 4) << 3);
      int col = g * 512 + ht * 16 + (lane & 15);
#pragma unroll
      for (int j = 0; j < 8; j++)
        Wpk[t * 8 + j] = f2bf(W_hh[(k0 + j) * 2048 + col]);
    } else if (t < 131072 + 32768) {      // W_ih: 32 ht * 4 g * 4 kit * 64 lanes
      int t2 = t - 131072;
      int lane = t2 & 63, row = t2 >> 6;
      int kit = row & 3, gh = row >> 2;
      int g = gh & 3, ht = gh >> 2;
      int k0 = kit * 32 + ((lane >> 4) << 3);
      int col = g * 512 + ht * 16 + (lane & 15);
#pragma unroll
      for (int j = 0; j < 8; j++)
        Wipk[t2 * 8 + j] = f2bf(W_ih[(k0 + j) * 2048 + col]);
    } else if (t < 131072 + 32768 + 2048) {
      int i = t - 131072 - 32768;
      bc[i] = b_ih[i] + b_hh[i];          // b_ih + b_hh folded together
    }
    return;
  }
  // ---- ctx: 4 batch rows/block; hid1 computed in-LDS (no global round trip) ----
  {
    __shared__ float hr[4 * H_];
    __shared__ float cc[4 * C_];
    int r0 = (bid - 2696) * 4, t = tid;
    if (t < 4 * C_) cc[t] = context[r0 * C_ + t];
    __syncthreads();
    for (int rj = t; rj < 4 * H_; rj += 256) {
      int r = rj >> 9, j = rj & 511;
      float acc = b1[j];
#pragma unroll 8
      for (int k = 0; k < C_; k++) acc = fmaf(cc[r * C_ + k], w1[k * H_ + j], acc);
      hr[rj] = fmaxf(acc, 0.f);
    }
    __syncthreads();
    float acc[4][6];
#pragma unroll
    for (int r = 0; r < 4; r++)
#pragma unroll
      for (int i = 0; i < 6; i++) acc[r][i] = 0.f;
    for (int k = 0; k < H_; k++) {
      float w[6];
#pragma unroll
      for (int i = 0; i < 6; i++) w[i] = w2[k * 1536 + t + i * 256];
#pragma unroll
      for (int r = 0; r < 4; r++) {
        float hv = hr[r * H_ + k];
#pragma unroll
        for (int i = 0; i < 6; i++) acc[r][i] = fmaf(hv, w[i], acc[r][i]);
      }
    }
#pragma unroll
    for (int r = 0; r < 4; r++)
#pragma unroll
      for (int i = 0; i < 6; i++) {
        int col = t + i * 256;
        ctxg[(r0 + r) * 1536 + col] = sigmoid_(acc[r][i] + b2[col]);
      }
  }
}

// ---------------------------------------------------------------------------
// Persistent LSTM kernel. Grid = 256 blocks (8 batch-tiles x 32 h-col tiles,
// static mapping: bt = blockIdx>>5, ht = blockIdx&31). Placement-independent.
// h exchange: producers write-through sc0 sc1 to L3 (R3-proven). Consumers:
//  - hmask==127 (unique buffer per step): loads use sc0 ONLY -> fill the
//    reader XCD's L2; each line fetched from L3 once per XCD, not per block.
//    No staleness: every address written exactly once per launch before any
//    read (t=0 reads nothing). sc0 still bypasses L1.
//  - hmask==1 (fallback, small ws): R3's 2-buffer rotation, sc0 sc1 loads.
// Step barrier: PER-WAVE monotonic flags (128/group). Arrive = own-wave
// vmcnt(0) drain + lane0 stores (t+1) -- no intra-block sync on the arrival
// path (R7's regression). Spin = 2 flag loads/lane + __all.
// ---------------------------------------------------------------------------
__global__ void __launch_bounds__(256) lstm_kernel(
    const unsigned short* __restrict__ xfr, const unsigned short* __restrict__ Wpk,
    const unsigned short* __restrict__ Wipk, const float* __restrict__ bc,
    const float* __restrict__ ctxg, float* __restrict__ hfinal,
    unsigned short* __restrict__ hbase, unsigned int* __restrict__ flags,
    int hmask) {
  __shared__ __align__(16) unsigned short lds_h[16384];  // 2R x 16kit x 512  (32 KB)
  __shared__ __align__(16) unsigned short lds_x[4096];   // 2R x 4kit x 512   (8 KB)
  __shared__ float lds_g[128 * 17];                      // stride 17: conflict-light

  int tid = threadIdx.x, lane = tid & 63, wid = tid >> 6;
  int bt = blockIdx.x >> 5, ht = blockIdx.x & 31;        // static mapping
  const bool cached = (hmask == 127);

  // --- prologue: resident weight fragments (coalesced 16B/lane loads) ---
  short8 wf[16], wfi[4];
  {
    const short8* wp = (const short8*)Wpk + (ht * 4 + wid) * 16 * 64 + lane;
#pragma unroll
    for (int kit = 0; kit < 16; kit++) wf[kit] = wp[kit * 64];
    const short8* wip = (const short8*)Wipk + (ht * 4 + wid) * 4 * 64 + lane;
#pragma unroll
    for (int kit = 0; kit < 4; kit++) wfi[kit] = wip[kit * 64];
  }

  // --- per-thread elementwise state: 2 adjacent j's (one packed uint store) ---
  int bl = tid >> 3, jl0 = (tid & 7) * 2;       // bl in [0,32), jl0 even
  int bglob = bt * 32 + bl;
  int j0 = ht * 16 + jl0;
  float cst[2] = {0.f, 0.f};
  float ci_[2], cf_[2], co_[2], bi_[2], bf_[2], bg_[2], bo_[2];
#pragma unroll
  for (int p = 0; p < 2; p++) {
    int j = j0 + p;
    ci_[p] = ctxg[bglob * 1536 + j];
    cf_[p] = ctxg[bglob * 1536 + 512 + j];
    co_[p] = ctxg[bglob * 1536 + 1024 + j];
    bi_[p] = bc[j]; bf_[p] = bc[512 + j]; bg_[p] = bc[1024 + j]; bo_[p] = bc[1536 + j];
  }
  // fragment-major short offset of (bglob, j0); /2 -> packed uint offset
  int hoff2 = (((bt * 2 + (bl >> 4)) * 64 + ht * 2 + (jl0 >> 3)) * 128
               + (bl & 15) * 8 + (jl0 & 7)) >> 1;

  unsigned int* myflag = flags + bt * 128 + ht * 4 + wid;  // per-WAVE flag
  const unsigned int* fp0 = flags + bt * 128 + lane;       // spin: 2 flags/lane
  const unsigned int* fp1 = fp0 + 64;

  // --- stage x(0) ---
#pragma unroll
  for (int i = 0; i < 2; i++) {
    int c = wid * 2 + i, R = c >> 2, kit = c & 3;
    u4 d = *(const u4*)(xfr + (size_t)((bt * 2 + R) * 16 + kit * 4) * 128 + lane * 8);
    *(u4*)(lds_x + (R * 4 + kit) * 512 + lane * 8) = d;
  }
  __syncthreads();

  for (int t = 0; t < S_; t++) {
    const unsigned short* hread = hbase + (size_t)((t - 1) & hmask) * (B_ * H_);
    unsigned short* hwrite = (unsigned short*)hbase + (size_t)(t & hmask) * (B_ * H_);

    f4 acc0a = {0.f, 0.f, 0.f, 0.f}, acc1a = {0.f, 0.f, 0.f, 0.f};
    f4 acc0b = {0.f, 0.f, 0.f, 0.f}, acc1b = {0.f, 0.f, 0.f, 0.f};

    if (t > 0) {
      // --- spin: 2 coalesced flag loads per lane + __all (no RMW) ---
      unsigned tgt = (unsigned)t;
      for (;;) {
        unsigned a = __hip_atomic_load(fp0, __ATOMIC_RELAXED, __HIP_MEMORY_SCOPE_AGENT);
        unsigned b = __hip_atomic_load(fp1, __ATOMIC_RELAXED, __HIP_MEMORY_SCOPE_AGENT);
        unsigned v = (a < b) ? a : b;
        if (__all(v >= tgt)) break;
      }

      // --- issue h loads (coalesced dwordx4; L2-cacheable in unique mode) ---
      u4 tmp[8];
#pragma unroll
      for (int i = 0; i < 8; i++) {
        int c = wid * 8 + i, R = c >> 4, kit = c & 15;
        const unsigned int* src = (const unsigned int*)hread
            + (bt * 2 + R) * 4096 + kit * 256 + lane * 4;
        if (cached)
          asm volatile("global_load_dwordx4 %0, %1, off sc0"
                       : "=v"(tmp[i]) : "v"(src) : "memory");
        else
          asm volatile("global_load_dwordx4 %0, %1, off sc0 sc1"
                       : "=v"(tmp[i]) : "v"(src) : "memory");
      }

      // --- x MFMAs while the h loads are in flight (R3 ordering) ---
#pragma unroll
      for (int kit = 0; kit < 4; kit++) {
        short8 a0 = *(const short8*)(lds_x + kit * 512 + lane * 8);
        short8 a1 = *(const short8*)(lds_x + 2048 + kit * 512 + lane * 8);
        if (kit & 1) {
          acc0b = __builtin_amdgcn_mfma_f32_16x16x32_bf16(a0, wfi[kit], acc0b, 0, 0, 0);
          acc1b = __builtin_amdgcn_mfma_f32_16x16x32_bf16(a1, wfi[kit], acc1b, 0, 0, 0);
        } else {
          acc0a = __builtin_amdgcn_mfma_f32_16x16x32_bf16(a0, wfi[kit], acc0a, 0, 0, 0);
          acc1a = __builtin_amdgcn_mfma_f32_16x16x32_bf16(a1, wfi[kit], acc1a, 0, 0, 0);
        }
      }

      // --- drain h loads (values tied to the waitcnt), stage to LDS ---
      asm volatile("s_waitcnt vmcnt(0)"
                   : "+v"(tmp[0]), "+v"(tmp[1]), "+v"(tmp[2]), "+v"(tmp[3]),
                     "+v"(tmp[4]), "+v"(tmp[5]), "+v"(tmp[6]), "+v"(tmp[7])
                   :: "memory");
#pragma unroll
      for (int i = 0; i < 8; i++) {
        int c = wid * 8 + i, R = c >> 4, kit = c & 15;
        *(u4*)(lds_h + R * 8192 + kit * 512 + lane * 8) = tmp[i];
      }
      __syncthreads();

      // --- h MFMAs (split accumulators: halve the dependent-MFMA chain) ---
#pragma unroll
      for (int kit = 0; kit < 16; kit++) {
        short8 a0 = *(const short8*)(lds_h + kit * 512 + lane * 8);
        short8 a1 = *(const short8*)(lds_h + 8192 + kit * 512 + lane * 8);
        if (kit & 1) {
          acc0b = __builtin_amdgcn_mfma_f32_16x16x32_bf16(a0, wf[kit], acc0b, 0, 0, 0);
          acc1b = __builtin_amdgcn_mfma_f32_16x16x32_bf16(a1, wf[kit], acc1b, 0, 0, 0);
        } else {
          acc0a = __builtin_amdgcn_mfma_f32_16x16x32_bf16(a0, wf[kit], acc0a, 0, 0, 0);
          acc1a = __builtin_amdgcn_mfma_f32_16x16x32_bf16(a1, wf[kit], acc1a, 0, 0, 0);
        }
      }
    } else {
      // t == 0: h = 0, gates = x part only
#pragma unroll
      for (int kit = 0; kit < 4; kit++) {
        short8 a0 = *(const short8*)(lds_x + kit * 512 + lane * 8);
        short8 a1 = *(const short8*)(lds_x + 2048 + kit * 512 + lane * 8);
        acc0a = __builtin_amdgcn_mfma_f32_16x16x32_bf16(a0, wfi[kit], acc0a, 0, 0, 0);
        acc1a = __builtin_amdgcn_mfma_f32_16x16x32_bf16(a1, wfi[kit], acc1a, 0, 0, 0);
      }
    }

    // --- cross-gate combine: wave g publishes its gate block to LDS ---
    {
      f4 s0, s1;
#pragma unroll
      for (int r = 0; r < 4; r++) { s0[r] = acc0a[r] + acc0b[r]; s1[r] = acc1a[r] + acc1b[r]; }
      int q = lane >> 4, n = lane & 15;
#pragma unroll
      for (int r = 0; r < 4; r++) {
        lds_g[(wid * 32 + q * 4 + r) * 17 + n] = s0[r];          // rows 0..15
        lds_g[(wid * 32 + 16 + q * 4 + r) * 17 + n] = s1[r];     // rows 16..31
      }
    }
    __syncthreads();

    // --- elementwise LSTM cell update (fp32), packed bf16x2 write-through ---
    {
      float hv[2];
#pragma unroll
      for (int p = 0; p < 2; p++) {
        int jl = jl0 + p;
        float gi = lds_g[(0 * 32 + bl) * 17 + jl] + bi_[p];
        float gf = lds_g[(1 * 32 + bl) * 17 + jl] + bf_[p];
        float gg = lds_g[(2 * 32 + bl) * 17 + jl] + bg_[p];
        float go = lds_g[(3 * 32 + bl) * 17 + jl] + bo_[p];
        float iv = ci_[p] * sigmoid_(gi);
        float fv = cf_[p] * sigmoid_(gf);
        float ov = co_[p] * sigmoid_(go);
        float gv = tanh_(gg);
        float c = fv * cst[p] + iv * gv;
        cst[p] = c;
        hv[p] = ov * tanh_(c);
      }
      unsigned int packed = (unsigned)f2bf(hv[0]) | ((unsigned)f2bf(hv[1]) << 16);
      unsigned int* dst = (unsigned int*)hwrite + hoff2;
      asm volatile("global_store_dword %0, %1, off sc0 sc1"
                   :: "v"(dst), "v"(packed) : "memory");
      if (t == S_ - 1) {
        hfinal[bglob * H_ + j0] = hv[0];
        hfinal[bglob * H_ + j0 + 1] = hv[1];
      }
    }

    if (t < S_ - 1) {
      // --- per-WAVE arrive: drain own stores, lane0 stores flag. No block
      //     sync on the arrival path (R7's regression). ---
      asm volatile("s_waitcnt vmcnt(0)" ::: "memory");
      if (lane == 0) {
        unsigned val = (unsigned)(t + 1);
        asm volatile("global_store_dword %0, %1, off sc0 sc1"
                     :: "v"(myflag), "v"(val) : "memory");
      }
      // --- stage x(t+1) while others arrive ---
#pragma unroll
      for (int i = 0; i < 2; i++) {
        int c = wid * 2 + i, R = c >> 2, kit = c & 3;
        u4 d = *(const u4*)(xfr + (size_t)((((t + 1) * 16) + bt * 2 + R) * 16 + kit * 4) * 128 + lane * 8);
        *(u4*)(lds_x + (R * 4 + kit) * 512 + lane * 8) = d;
      }
    }
    __syncthreads();   // gates lds_x(t+1) reads and lds_g reuse
  }
}

// ---------------------------------------------------------------------------
// VAE head: mu/lv = h@W + b, z = mu + eps*exp(0.5*lv),
// recon = relu(z@dec_w1+db1)@dec_w2+db2. One block per batch row, all fp32.
// ---------------------------------------------------------------------------
__global__ void post_kernel(const float* __restrict__ hfinal, const float* __restrict__ eps,
                            const float* __restrict__ mu_w, const float* __restrict__ mu_b,
                            const float* __restrict__ lv_w, const float* __restrict__ lv_b,
                            const float* __restrict__ dw1, const float* __restrict__ db1,
                            const float* __restrict__ dw2, const float* __restrict__ db2,
                            float* __restrict__ out) {
  __shared__ float sh[H_], sh1[H_], smu[L_], slv[L_], sz[L_];
  int b = blockIdx.x, t = threadIdx.x;
  for (int i = t; i < H_; i += 256) sh[i] = hfinal[b * H_ + i];
  __syncthreads();
  {
    int o = t >> 3, sub = t & 7, l = o & 15;   // 32 outputs x 8-lane partial dots
    const float* w = (o < 16) ? mu_w : lv_w;
    float acc = 0.f;
    int k0 = sub * 64;
#pragma unroll 8
    for (int k = k0; k < k0 + 64; k++) acc = fmaf(sh[k], w[k * L_ + l], acc);
#pragma unroll
    for (int d = 4; d >= 1; d >>= 1) acc += __shfl_down(acc, d, 8);
    if (sub == 0) {
      if (o < 16) { float v = acc + mu_b[l]; smu[l] = v; out[32768 + b * 16 + l] = v; }
      else        { float v = acc + lv_b[l]; slv[l] = v; out[36864 + b * 16 + l] = v; }
    }
  }
  __syncthreads();
  if (t < L_) sz[t] = smu[t] + eps[b * L_ + t] * __expf(0.5f * slv[t]);
  __syncthreads();
  for (int j = t; j < H_; j += 256) {
    float acc = db1[j];
#pragma unroll
    for (int l = 0; l < L_; l++) acc = fmaf(sz[l], dw1[l * H_ + j], acc);
    sh1[j] = fmaxf(acc, 0.f);
  }
  __syncthreads();
  if (t < F_) {
    float acc = db2[t];
    for (int k = 0; k < H_; k++) acc = fmaf(sh1[k], dw2[k * F_ + t], acc);
    out[b * F_ + t] = acc;
  }
}

// ---------------------------------------------------------------------------
extern "C" void kernel_launch(void* const* d_in, const int* in_sizes, int n_in,
                              void* d_out, int out_size, void* d_ws, size_t ws_size,
                              hipStream_t stream) {
  const float* x      = (const float*)d_in[0];
  const float* ctxin  = (const float*)d_in[1];
  const float* eps    = (const float*)d_in[2];
  const float* W_ih   = (const float*)d_in[3];
  const float* b_ih   = (const float*)d_in[4];
  const float* W_hh   = (const float*)d_in[5];
  const float* b_hh   = (const float*)d_in[6];
  const float* cg_w1  = (const float*)d_in[7];
  const float* cg_b1  = (const float*)d_in[8];
  const float* cg_w2  = (const float*)d_in[9];
  const float* cg_b2  = (const float*)d_in[10];
  const float* mu_w   = (const float*)d_in[11];
  const float* mu_b   = (const float*)d_in[12];
  const float* lv_w   = (const float*)d_in[13];
  const float* lv_b   = (const float*)d_in[14];
  const float* dec_w1 = (const float*)d_in[15];
  const float* dec_b1 = (const float*)d_in[16];
  const float* dec_w2 = (const float*)d_in[17];
  const float* dec_b2 = (const float*)d_in[18];
  float* out = (float*)d_out;

  char* ws = (char*)d_ws;
  size_t off = 0;
  auto alloc = [&](size_t bytes) { char* p = ws + off; off = (off + bytes + 255) & ~(size_t)255; return p; };

  unsigned int* flags = (unsigned int*)alloc(8 * 128 * 4);    // per-wave monotonic flags
  size_t zero_bytes = off;
  unsigned short* xfr  = (unsigned short*)alloc((size_t)B_ * S_ * F_ * 2);  // 8 MB
  unsigned short* Wpk  = (unsigned short*)alloc((size_t)H_ * 2048 * 2);     // 2 MB
  unsigned short* Wipk = (unsigned short*)alloc((size_t)F_ * 2048 * 2);     // 512 KB
  float* bc    = (float*)alloc(2048 * 4);
  float* ctxg  = (float*)alloc((size_t)B_ * 1536 * 4);
  float* hfin  = (float*)alloc((size_t)B_ * H_ * 4);
  // h buffers last: unique-per-step (32 MB) if ws allows, else 2-buffer rotation
  size_t h_unique_bytes = (size_t)S_ * B_ * H_ * 2;           // 32 MB
  int hmask;
  unsigned short* hbase;
  if (ws_size >= off + h_unique_bytes) {
    hbase = (unsigned short*)alloc(h_unique_bytes);
    hmask = 127;                       // buffer index = t (S_=128 steps)
  } else {
    hbase = (unsigned short*)alloc((size_t)2 * B_ * H_ * 2);  // 512 KB
    hmask = 1;                         // classic double buffer
  }
  (void)in_sizes; (void)n_in; (void)out_size;

  hipMemsetAsync(d_ws, 0, zero_bytes, stream);   // flags only (h needs no init)

  prep_kernel<<<2760, 256, 0, stream>>>(x, W_hh, W_ih, b_ih, b_hh, ctxin,
                                        cg_w1, cg_b1, cg_w2, cg_b2,
                                        xfr, Wpk, Wipk, bc, ctxg);
  lstm_kernel<<<256, 256, 0, stream>>>(xfr, Wpk, Wipk, bc, ctxg, hfin,
                                       hbase, flags, hmask);
  post_kernel<<<256, 256, 0, stream>>>(hfin, eps, mu_w, mu_b, lv_w, lv_b,
                                       dec_w1, dec_b1, dec_w2, dec_b2, out);
}